// Round 16
// baseline (1719.148 us; speedup 1.0000x reference)
//
#include <hip/hip_runtime.h>
#include <stdint.h>

#define NB 64
#define DD 256
#define HH 512
#define NGROUP 2048
#define NPERS 256   // persistent blocks (1 per CU); 8 groups each

typedef __attribute__((ext_vector_type(8))) _Float16 half8;
typedef __attribute__((ext_vector_type(4))) _Float16 half4;
typedef __attribute__((ext_vector_type(4))) float f32x4;

__device__ __forceinline__ half8 ld8(const _Float16* p) {
    return *reinterpret_cast<const half8*>(p);
}

// Fragment-packing index (R12, validated): matrix element [R][K]
__device__ __forceinline__ int fragidx(int R, int K, int NKS) {
    return (((R >> 4) * NKS + (K >> 5)) * 64 + (((K >> 3) & 3) * 16 + (R & 15))) * 8 + (K & 7);
}

// ---------------- merged prep kernel (R12/R15, validated) ----------------
__global__ void prep_all(const float* __restrict__ Wq1, const float* __restrict__ Wk1,
                         const float* __restrict__ Wv1, const float* __restrict__ Wq2,
                         const float* __restrict__ Wk2, const float* __restrict__ Wv2,
                         const float* __restrict__ W1, const float* __restrict__ W2,
                         _Float16* __restrict__ Gf1, _Float16* __restrict__ Gf2,
                         _Float16* __restrict__ UTf, _Float16* __restrict__ W2Tf,
                         float scale) {
    const int b = blockIdx.x, t = threadIdx.x;
    if (b < 512) {
        const float* A = (b < 256) ? Wq1 : Wq2;
        const float* Bm = (b < 256) ? Wk2 : Wk1;
        _Float16* G = (b < 256) ? Gf1 : Gf2;
        const int d = b & 255, e = t;
        const float4* qa = reinterpret_cast<const float4*>(A + d * HH);
        const float4* ka = reinterpret_cast<const float4*>(Bm + e * HH);
        float s = 0.f;
        #pragma unroll 8
        for (int j = 0; j < HH / 4; ++j) {
            float4 a = qa[j], bb = ka[j];
            s += a.x * bb.x + a.y * bb.y + a.z * bb.z + a.w * bb.w;
        }
        G[fragidx(d, e, 8)] = (_Float16)(s * scale);
    } else if (b < 1536) {
        const int half = (b - 512) >> 9;
        const int o = (b - 512) & 511;
        const float* Wv = half ? Wv2 : Wv1;
        const float* W1p = W1 + half * HH * HH;
        const int d = t;
        const float4* va = reinterpret_cast<const float4*>(Wv + d * HH);
        float s = 0.f;
        #pragma unroll 4
        for (int j4 = 0; j4 < HH / 4; ++j4) {
            float4 a = va[j4];
            const int j = j4 * 4;
            s += a.x * W1p[(j + 0) * HH + o];
            s += a.y * W1p[(j + 1) * HH + o];
            s += a.z * W1p[(j + 2) * HH + o];
            s += a.w * W1p[(j + 3) * HH + o];
        }
        UTf[fragidx(o, half * 256 + d, 16)] = (_Float16)s;
    } else {
        __shared__ float tile[32][33];
        const int bi = b - 1536;
        const int bk = (bi & 15) * 32;
        const int bh = (bi >> 4) * 32;
        const int tx = t & 31, ty = t >> 5;
        #pragma unroll
        for (int i = 0; i < 32; i += 8)
            tile[ty + i][tx] = W2[(bh + ty + i) * HH + bk + tx];
        __syncthreads();
        #pragma unroll
        for (int i = 0; i < 32; i += 8) {
            const int R = bk + ty + i;
            const int K = bh + tx;
            W2Tf[fragidx(R, K, 16)] = (_Float16)tile[tx][ty + i];
        }
    }
}

// ---------------- main fused kernel (R15 phases; persistent + x-prefetch) ------
// 1024 thr (16 waves), 144 KiB LDS, 1 blk/CU, 4 waves/SIMD, 8 groups per block.
//   X  @ 0       [2][64][256] f16 ext-swz -> becomes g1,g2 (re-staged per group)
//   A  @ 65536   [2][64][256] f16         -> XT [2][256][64] -> h [64][512]
//   P  @ 131072  [2][64][64] f16
#define ABASE 65536
#define PBASE 131072

__device__ __forceinline__ int axX(int side, int row, int ec) {
    return side * 32768 + row * 512 +
           ((2 * ec) ^ ((row & 7) << 4) ^ (((row >> 3) & 1) << 7));
}
__device__ __forceinline__ int axA(int side, int row, int ec) {
    return ABASE + side * 32768 + row * 512 +
           ((2 * ec) ^ ((row & 7) << 4) ^ (((row >> 3) & 1) << 7));
}
__device__ __forceinline__ int axXT(int side, int row, int ec) {   // [256][64], 128B rows
    return ABASE + side * 32768 + row * 128 + ((2 * ec) ^ ((row & 7) << 4));
}
__device__ __forceinline__ int axH(int row, int ec) {              // [64][512], 1024B rows
    return ABASE + row * 1024 +
           ((2 * ec) ^ ((row & 7) << 4) ^ (((row >> 3) & 1) << 7));
}
__device__ __forceinline__ int axP(int side, int row, int ec) {    // [64][64], 128B rows
    return PBASE + side * 8192 + row * 128 + ((2 * ec) ^ ((row & 7) << 4));
}

__global__ __launch_bounds__(1024, 4)
void fused_kernel(const float* __restrict__ x1g, const float* __restrict__ x2g,
                  const _Float16* __restrict__ Gf1, const _Float16* __restrict__ Gf2,
                  const _Float16* __restrict__ UTf, const _Float16* __restrict__ W2Tf,
                  const float* __restrict__ b1, const float* __restrict__ b2,
                  float* __restrict__ out) {
    __shared__ __align__(16) char lds[147456];

    const int tid = threadIdx.x;
    const int lane = tid & 63;
    const int w = tid >> 6;        // wave 0..15
    const int c = lane & 15;
    const int kg = lane >> 4;
    const int s = w >> 3;          // side (waves 0-7: side0, 8-15: side1)
    const int ws = w & 7;          // 32-wide strip index within side
    const f32x4 z = {0.f, 0.f, 0.f, 0.f};

    // ---- prologue: stage group g0 ----
    {
        const size_t g0 = (size_t)blockIdx.x * 8;
        const float* xs0 = x1g + g0 * (NB * DD);
        const float* xs1 = x2g + g0 * (NB * DD);
        #pragma unroll
        for (int it = 0; it < 4; ++it) {
            const int row = 4 * w + it;
            float4 a = reinterpret_cast<const float4*>(xs0 + row * DD)[lane];
            float4 b = reinterpret_cast<const float4*>(xs1 + row * DD)[lane];
            half4 ha, hb;
            ha[0] = (_Float16)a.x; ha[1] = (_Float16)a.y; ha[2] = (_Float16)a.z; ha[3] = (_Float16)a.w;
            hb[0] = (_Float16)b.x; hb[1] = (_Float16)b.y; hb[2] = (_Float16)b.z; hb[3] = (_Float16)b.w;
            *reinterpret_cast<half4*>(lds + axX(0, row, 4 * lane)) = ha;
            *reinterpret_cast<half4*>(lds + axX(1, row, 4 * lane)) = hb;
        }
    }
    __syncthreads();

    #pragma unroll 1
    for (int itg = 0; itg < 8; ++itg) {
        const size_t g = (size_t)blockIdx.x * 8 + itg;

        // ==== P2: A-full. slotA[s] = X_{1-s} @ Gsel^T; wave owns 32 d-cols ====
        {
            const _Float16* Gsel = s ? Gf2 : Gf1;
            const int xo = 1 - s;
            f32x4 acc[4][2];
            #pragma unroll
            for (int i = 0; i < 4; ++i) { acc[i][0] = z; acc[i][1] = z; }
            #pragma unroll
            for (int ks = 0; ks < 8; ++ks) {
                half8 af[4];
                #pragma unroll
                for (int i = 0; i < 4; ++i)
                    af[i] = *reinterpret_cast<const half8*>(lds + axX(xo, 16 * i + c, 32 * ks + 8 * kg));
                #pragma unroll
                for (int ct = 0; ct < 2; ++ct) {
                    half8 bf = ld8(Gsel + (((2 * ws + ct) * 8 + ks) * 64 + lane) * 8);
                    #pragma unroll
                    for (int i = 0; i < 4; ++i)
                        acc[i][ct] = __builtin_amdgcn_mfma_f32_16x16x32_f16(af[i], bf, acc[i][ct], 0, 0, 0);
                }
            }
            #pragma unroll
            for (int i = 0; i < 4; ++i)
                #pragma unroll
                for (int ct = 0; ct < 2; ++ct)
                    #pragma unroll
                    for (int r = 0; r < 4; ++r)
                        *reinterpret_cast<_Float16*>(lds + axA(s, 16 * i + 4 * kg + r, 32 * ws + 16 * ct + c)) = (_Float16)acc[i][ct][r];
        }
        __syncthreads();

        // ==== P3: S (K=256) + softmax -> P[s]; 8 active waves ====
        if ((w & 4) == 0) {
            const int wa = w & 3;
            f32x4 Sacc[4] = {z, z, z, z};
            #pragma unroll
            for (int ks = 0; ks < 8; ++ks) {
                half8 af = *reinterpret_cast<const half8*>(lds + axX(s, 16 * wa + c, 32 * ks + 8 * kg));
                #pragma unroll
                for (int j = 0; j < 4; ++j) {
                    half8 bfr = *reinterpret_cast<const half8*>(lds + axA(s, 16 * j + c, 32 * ks + 8 * kg));
                    Sacc[j] = __builtin_amdgcn_mfma_f32_16x16x32_f16(af, bfr, Sacc[j], 0, 0, 0);
                }
            }
            #pragma unroll
            for (int r = 0; r < 4; ++r) {
                float m0 = fmaxf(fmaxf(Sacc[0][r], Sacc[1][r]), fmaxf(Sacc[2][r], Sacc[3][r]));
                m0 = fmaxf(m0, __shfl_xor(m0, 1));
                m0 = fmaxf(m0, __shfl_xor(m0, 2));
                m0 = fmaxf(m0, __shfl_xor(m0, 4));
                m0 = fmaxf(m0, __shfl_xor(m0, 8));
                float e0 = __expf(Sacc[0][r] - m0);
                float e1 = __expf(Sacc[1][r] - m0);
                float e2 = __expf(Sacc[2][r] - m0);
                float e3 = __expf(Sacc[3][r] - m0);
                float s0 = e0 + e1 + e2 + e3;
                s0 += __shfl_xor(s0, 1);
                s0 += __shfl_xor(s0, 2);
                s0 += __shfl_xor(s0, 4);
                s0 += __shfl_xor(s0, 8);
                const float inv = 1.f / s0;
                const int row = 16 * wa + 4 * kg + r;
                *reinterpret_cast<_Float16*>(lds + axP(s, row, 16 * 0 + c)) = (_Float16)(e0 * inv);
                *reinterpret_cast<_Float16*>(lds + axP(s, row, 16 * 1 + c)) = (_Float16)(e1 * inv);
                *reinterpret_cast<_Float16*>(lds + axP(s, row, 16 * 2 + c)) = (_Float16)(e2 * inv);
                *reinterpret_cast<_Float16*>(lds + axP(s, row, 16 * 3 + c)) = (_Float16)(e3 * inv);
            }
        }
        __syncthreads();

        // ==== P4: XT build over slotA (A dead) ====
        {
            #pragma unroll
            for (int jj = 0; jj < 4; ++jj) {
                half8 v = *reinterpret_cast<const half8*>(lds + axX(s, lane, 32 * ws + 8 * jj));
                #pragma unroll
                for (int e = 0; e < 8; ++e)
                    *reinterpret_cast<_Float16*>(lds + axXT(s, 32 * ws + 8 * jj + e, lane)) = v[e];
            }
        }
        __syncthreads();

        // ==== P5: PV. g_s[:, 32ws..] = P_s @ X_s via XT; g overwrites X_s ====
        {
            half8 paf[4][2];
            #pragma unroll
            for (int i = 0; i < 4; ++i)
                #pragma unroll
                for (int ksp = 0; ksp < 2; ++ksp)
                    paf[i][ksp] = *reinterpret_cast<const half8*>(lds + axP(s, 16 * i + c, 32 * ksp + 8 * kg));
            #pragma unroll
            for (int dt = 0; dt < 2; ++dt) {
                half8 bfr0 = *reinterpret_cast<const half8*>(lds + axXT(s, 32 * ws + 16 * dt + c, 8 * kg));
                half8 bfr1 = *reinterpret_cast<const half8*>(lds + axXT(s, 32 * ws + 16 * dt + c, 32 + 8 * kg));
                #pragma unroll
                for (int i = 0; i < 4; ++i) {
                    f32x4 acc = z;
                    acc = __builtin_amdgcn_mfma_f32_16x16x32_f16(paf[i][0], bfr0, acc, 0, 0, 0);
                    acc = __builtin_amdgcn_mfma_f32_16x16x32_f16(paf[i][1], bfr1, acc, 0, 0, 0);
                    #pragma unroll
                    for (int r = 0; r < 4; ++r)
                        *reinterpret_cast<_Float16*>(lds + axX(s, 16 * i + 4 * kg + r, 32 * ws + 16 * dt + c)) = (_Float16)acc[r];
                }
            }
        }
        __syncthreads();

        // ==== prefetch next group's x into registers (loads overlap P6+P7) ====
        float4 nx0[4], nx1[4];
        const size_t gn = (size_t)blockIdx.x * 8 + ((itg < 7) ? (itg + 1) : itg);
        {
            const float* xs0 = x1g + gn * (NB * DD);
            const float* xs1 = x2g + gn * (NB * DD);
            #pragma unroll
            for (int it = 0; it < 4; ++it) {
                const int row = 4 * w + it;
                nx0[it] = reinterpret_cast<const float4*>(xs0 + row * DD)[lane];
                nx1[it] = reinterpret_cast<const float4*>(xs1 + row * DD)[lane];
            }
        }

        // ==== P6: h-full = relu(g @ U + b1) -> h[64][512]; wave: 32 h-cols ====
        {
            f32x4 acc[4][2];
            #pragma unroll
            for (int i = 0; i < 4; ++i) { acc[i][0] = z; acc[i][1] = z; }
            #pragma unroll
            for (int ks = 0; ks < 16; ++ks) {
                const int side = ks >> 3, kk = ks & 7;
                half8 af[4];
                #pragma unroll
                for (int i = 0; i < 4; ++i)
                    af[i] = *reinterpret_cast<const half8*>(lds + axX(side, 16 * i + c, 32 * kk + 8 * kg));
                #pragma unroll
                for (int ct = 0; ct < 2; ++ct) {
                    half8 bf = ld8(UTf + (((2 * w + ct) * 16 + ks) * 64 + lane) * 8);
                    #pragma unroll
                    for (int i = 0; i < 4; ++i)
                        acc[i][ct] = __builtin_amdgcn_mfma_f32_16x16x32_f16(af[i], bf, acc[i][ct], 0, 0, 0);
                }
            }
            #pragma unroll
            for (int ct = 0; ct < 2; ++ct) {
                const float bb = b1[32 * w + 16 * ct + c];
                #pragma unroll
                for (int i = 0; i < 4; ++i)
                    #pragma unroll
                    for (int r = 0; r < 4; ++r)
                        *reinterpret_cast<_Float16*>(lds + axH(16 * i + 4 * kg + r, 32 * w + 16 * ct + c)) =
                            (_Float16)fmaxf(acc[i][ct][r] + bb, 0.f);
            }
        }
        __syncthreads();   // h ready; X region now dead

        // ==== P7: out^T = W2T-rows x h (K=512) + b2; wave: 32 ocols ====
        {
            f32x4 oacc[2][4];
            #pragma unroll
            for (int i = 0; i < 2; ++i)
                #pragma unroll
                for (int nj = 0; nj < 4; ++nj) oacc[i][nj] = z;
            #pragma unroll
            for (int ks = 0; ks < 16; ++ks) {
                half8 bfr2[4];
                #pragma unroll
                for (int nj = 0; nj < 4; ++nj)
                    bfr2[nj] = *reinterpret_cast<const half8*>(lds + axH(16 * nj + c, 32 * ks + 8 * kg));
                #pragma unroll
                for (int i = 0; i < 2; ++i) {
                    half8 af2 = ld8(W2Tf + (((2 * w + i) * 16 + ks) * 64 + lane) * 8);
                    #pragma unroll
                    for (int nj = 0; nj < 4; ++nj)
                        oacc[i][nj] = __builtin_amdgcn_mfma_f32_16x16x32_f16(af2, bfr2[nj], oacc[i][nj], 0, 0, 0);
                }
            }
            // stage next-x into X region (dead since post-P6 barrier)
            if (itg < 7) {
                #pragma unroll
                for (int it = 0; it < 4; ++it) {
                    const int row = 4 * w + it;
                    half4 ha, hb;
                    ha[0] = (_Float16)nx0[it].x; ha[1] = (_Float16)nx0[it].y;
                    ha[2] = (_Float16)nx0[it].z; ha[3] = (_Float16)nx0[it].w;
                    hb[0] = (_Float16)nx1[it].x; hb[1] = (_Float16)nx1[it].y;
                    hb[2] = (_Float16)nx1[it].z; hb[3] = (_Float16)nx1[it].w;
                    *reinterpret_cast<half4*>(lds + axX(0, row, 4 * lane)) = ha;
                    *reinterpret_cast<half4*>(lds + axX(1, row, 4 * lane)) = hb;
                }
            }
            // epilogue: nj outer, i inner (R15 coalesced order)
            float* og = out + g * (size_t)(NB * HH);
            #pragma unroll
            for (int nj = 0; nj < 4; ++nj) {
                float* orow = og + (size_t)(16 * nj + c) * HH;
                #pragma unroll
                for (int i = 0; i < 2; ++i) {
                    const int ocol0 = 32 * w + 16 * i + 4 * kg;
                    const float4 b2v = *reinterpret_cast<const float4*>(b2 + ocol0);
                    float4 res;
                    res.x = oacc[i][nj][0] + b2v.x;
                    res.y = oacc[i][nj][1] + b2v.y;
                    res.z = oacc[i][nj][2] + b2v.z;
                    res.w = oacc[i][nj][3] + b2v.w;
                    *reinterpret_cast<float4*>(orow + ocol0) = res;
                }
            }
        }
        __syncthreads();   // X writes visible; h reads done -> next P2 may write A
    }
}

// ---------------- launch ----------------

extern "C" void kernel_launch(void* const* d_in, const int* in_sizes, int n_in,
                              void* d_out, int out_size, void* d_ws, size_t ws_size,
                              hipStream_t stream) {
    (void)in_sizes; (void)n_in; (void)out_size; (void)ws_size;
    const float* x1  = (const float*)d_in[0];
    const float* x2  = (const float*)d_in[1];
    const float* Wq1 = (const float*)d_in[2];
    const float* Wk1 = (const float*)d_in[3];
    const float* Wv1 = (const float*)d_in[4];
    const float* Wq2 = (const float*)d_in[5];
    const float* Wk2 = (const float*)d_in[6];
    const float* Wv2 = (const float*)d_in[7];
    const float* W1  = (const float*)d_in[8];
    const float* b1  = (const float*)d_in[9];
    const float* W2  = (const float*)d_in[10];
    const float* b2  = (const float*)d_in[11];
    float* out = (float*)d_out;

    char* ws = (char*)d_ws;
    _Float16* Gf1  = (_Float16*)(ws + 0);
    _Float16* Gf2  = (_Float16*)(ws + 131072);
    _Float16* UTf  = (_Float16*)(ws + 262144);
    _Float16* W2Tf = (_Float16*)(ws + 786432);

    const float scale = 0.0625f;  // D^-0.5

    prep_all<<<1792, 256, 0, stream>>>(Wq1, Wk1, Wv1, Wq2, Wk2, Wv2, W1, W2,
                                       Gf1, Gf2, UTf, W2Tf, scale);
    fused_kernel<<<NPERS, 1024, 0, stream>>>(x1, x2, Gf1, Gf2, UTf, W2Tf, b1, b2, out);
}

// Round 17
// 413.649 us; speedup vs baseline: 4.1561x; 4.1561x over previous
//
#include <hip/hip_runtime.h>
#include <stdint.h>

#define NB 64
#define DD 256
#define HH 512
#define NGROUP 2048

typedef __attribute__((ext_vector_type(8))) _Float16 half8;
typedef __attribute__((ext_vector_type(4))) _Float16 half4;
typedef __attribute__((ext_vector_type(4))) float f32x4;

__device__ __forceinline__ half8 ld8(const _Float16* p) {
    return *reinterpret_cast<const half8*>(p);
}

// Fragment-packing index (R12, validated): matrix element [R][K]
__device__ __forceinline__ int fragidx(int R, int K, int NKS) {
    return (((R >> 4) * NKS + (K >> 5)) * 64 + (((K >> 3) & 3) * 16 + (R & 15))) * 8 + (K & 7);
}

// ---------------- prep v2: LDS-staged, coalesced ----------------
// grid 384 x 256:
//   b in [0,64)    : G    — side=b>>5, dtile=b&31 (8 d-rows); thread = e
//   b in [64,128)  : UT   — half=(b-64)>>5, dtile=(b-64)&31; thread = o, o+256
//   b in [128,384) : W2T  — tile transpose (validated R12 path)
__global__ void prep_all(const float* __restrict__ Wq1, const float* __restrict__ Wk1,
                         const float* __restrict__ Wv1, const float* __restrict__ Wq2,
                         const float* __restrict__ Wk2, const float* __restrict__ Wv2,
                         const float* __restrict__ W1, const float* __restrict__ W2,
                         _Float16* __restrict__ Gf1, _Float16* __restrict__ Gf2,
                         _Float16* __restrict__ UTf, _Float16* __restrict__ W2Tf,
                         float scale) {
    __shared__ __align__(16) float stage[8][512];   // 16 KiB row staging
    __shared__ float tile[32][33];                  // W2T transpose tile
    const int b = blockIdx.x, t = threadIdx.x;

    if (b < 64) {
        // ---- G: G[d][e] = scale * dot(Wq[d,:], Wk[e,:]) ----
        const int side = b >> 5;            // 0: (Wq1,Wk2)->Gf1 ; 1: (Wq2,Wk1)->Gf2
        const int d0 = (b & 31) * 8;
        const float* Wq = side ? Wq2 : Wq1;
        const float* Wk = side ? Wk1 : Wk2;
        _Float16* G = side ? Gf2 : Gf1;
        // stage Wq rows d0..d0+7 (coalesced)
        #pragma unroll
        for (int it = 0; it < 4; ++it) {
            const int gi = t + 256 * it;            // float4 id
            const int row = gi >> 7, c4 = gi & 127;
            reinterpret_cast<float4*>(&stage[row][0])[c4] =
                reinterpret_cast<const float4*>(Wq + (size_t)(d0 + row) * HH)[c4];
        }
        __syncthreads();
        const int e = t;
        const float4* ka = reinterpret_cast<const float4*>(Wk + (size_t)e * HH);
        float s[8] = {0.f, 0.f, 0.f, 0.f, 0.f, 0.f, 0.f, 0.f};
        for (int j4 = 0; j4 < 128; ++j4) {
            const float4 v = ka[j4];
            #pragma unroll
            for (int dd = 0; dd < 8; ++dd) {
                const float4 q = reinterpret_cast<const float4*>(&stage[dd][0])[j4];
                s[dd] += v.x * q.x + v.y * q.y + v.z * q.z + v.w * q.w;
            }
        }
        #pragma unroll
        for (int dd = 0; dd < 8; ++dd)
            G[fragidx(d0 + dd, e, 8)] = (_Float16)(s[dd] * scale);
    } else if (b < 128) {
        // ---- UT: UT[o][half*256+d] = dot(Wv[d,:], W1p[:,o]) ----
        const int bi = b - 64;
        const int half = bi >> 5;
        const int d0 = (bi & 31) * 8;
        const float* Wv = half ? Wv2 : Wv1;
        const float* W1p = W1 + (size_t)half * HH * HH;
        // stage Wv rows d0..d0+7 (coalesced)
        #pragma unroll
        for (int it = 0; it < 4; ++it) {
            const int gi = t + 256 * it;
            const int row = gi >> 7, c4 = gi & 127;
            reinterpret_cast<float4*>(&stage[row][0])[c4] =
                reinterpret_cast<const float4*>(Wv + (size_t)(d0 + row) * HH)[c4];
        }
        __syncthreads();
        const int o0 = t, o1 = t + 256;
        float s0[8] = {0.f, 0.f, 0.f, 0.f, 0.f, 0.f, 0.f, 0.f};
        float s1[8] = {0.f, 0.f, 0.f, 0.f, 0.f, 0.f, 0.f, 0.f};
        for (int j4 = 0; j4 < 128; ++j4) {
            float4 qv[8];
            #pragma unroll
            for (int dd = 0; dd < 8; ++dd)
                qv[dd] = reinterpret_cast<const float4*>(&stage[dd][0])[j4];
            #pragma unroll
            for (int k = 0; k < 4; ++k) {
                const int j = 4 * j4 + k;
                const float w0 = W1p[(size_t)j * HH + o0];   // coalesced across lanes
                const float w1 = W1p[(size_t)j * HH + o1];
                #pragma unroll
                for (int dd = 0; dd < 8; ++dd) {
                    const float q = (k == 0) ? qv[dd].x : (k == 1) ? qv[dd].y
                                  : (k == 2) ? qv[dd].z : qv[dd].w;
                    s0[dd] += q * w0;
                    s1[dd] += q * w1;
                }
            }
        }
        #pragma unroll
        for (int dd = 0; dd < 8; ++dd) {
            UTf[fragidx(o0, half * 256 + d0 + dd, 16)] = (_Float16)s0[dd];
            UTf[fragidx(o1, half * 256 + d0 + dd, 16)] = (_Float16)s1[dd];
        }
    } else {
        // ---- W2T: pack W2^T into 16x16 fragment order (validated) ----
        const int bi = b - 128;
        const int bk = (bi & 15) * 32;
        const int bh = (bi >> 4) * 32;
        const int tx = t & 31, ty = t >> 5;
        #pragma unroll
        for (int i = 0; i < 32; i += 8)
            tile[ty + i][tx] = W2[(size_t)(bh + ty + i) * HH + bk + tx];
        __syncthreads();
        #pragma unroll
        for (int i = 0; i < 32; i += 8) {
            const int R = bk + ty + i;   // out col
            const int K = bh + tx;       // contraction (h)
            W2Tf[fragidx(R, K, 16)] = (_Float16)tile[tx][ty + i];
        }
    }
}

// ---------------- main fused kernel (R15 winner, verbatim) ------
// 1024 thr (16 waves), 144 KiB LDS, 1 blk/CU, 4 waves/SIMD.
//   X  @ 0       [2][64][256] f16 ext-swz -> becomes g1,g2
//   A  @ 65536   [2][64][256] f16         -> XT [2][256][64] -> h [64][512]
//   P  @ 131072  [2][64][64] f16
#define ABASE 65536
#define PBASE 131072

__device__ __forceinline__ int axX(int side, int row, int ec) {
    return side * 32768 + row * 512 +
           ((2 * ec) ^ ((row & 7) << 4) ^ (((row >> 3) & 1) << 7));
}
__device__ __forceinline__ int axA(int side, int row, int ec) {
    return ABASE + side * 32768 + row * 512 +
           ((2 * ec) ^ ((row & 7) << 4) ^ (((row >> 3) & 1) << 7));
}
__device__ __forceinline__ int axXT(int side, int row, int ec) {   // [256][64], 128B rows
    return ABASE + side * 32768 + row * 128 + ((2 * ec) ^ ((row & 7) << 4));
}
__device__ __forceinline__ int axH(int row, int ec) {              // [64][512], 1024B rows
    return ABASE + row * 1024 +
           ((2 * ec) ^ ((row & 7) << 4) ^ (((row >> 3) & 1) << 7));
}
__device__ __forceinline__ int axP(int side, int row, int ec) {    // [64][64], 128B rows
    return PBASE + side * 8192 + row * 128 + ((2 * ec) ^ ((row & 7) << 4));
}

__global__ __launch_bounds__(1024, 4)
void fused_kernel(const float* __restrict__ x1g, const float* __restrict__ x2g,
                  const _Float16* __restrict__ Gf1, const _Float16* __restrict__ Gf2,
                  const _Float16* __restrict__ UTf, const _Float16* __restrict__ W2Tf,
                  const float* __restrict__ b1, const float* __restrict__ b2,
                  float* __restrict__ out) {
    __shared__ __align__(16) char lds[147456];

    const int tid = threadIdx.x;
    const int lane = tid & 63;
    const int w = tid >> 6;        // wave 0..15
    const int c = lane & 15;
    const int kg = lane >> 4;
    const int s = w >> 3;          // side (waves 0-7: side0, 8-15: side1)
    const int ws = w & 7;          // 32-wide strip index within side
    const size_t g = blockIdx.x;
    const f32x4 z = {0.f, 0.f, 0.f, 0.f};

    // ==== P1: stage x -> f16 LDS ====
    {
        const float* xs0 = x1g + g * (NB * DD);
        const float* xs1 = x2g + g * (NB * DD);
        #pragma unroll
        for (int it = 0; it < 4; ++it) {
            const int row = 4 * w + it;
            float4 a = reinterpret_cast<const float4*>(xs0 + row * DD)[lane];
            float4 b = reinterpret_cast<const float4*>(xs1 + row * DD)[lane];
            half4 ha, hb;
            ha[0] = (_Float16)a.x; ha[1] = (_Float16)a.y; ha[2] = (_Float16)a.z; ha[3] = (_Float16)a.w;
            hb[0] = (_Float16)b.x; hb[1] = (_Float16)b.y; hb[2] = (_Float16)b.z; hb[3] = (_Float16)b.w;
            *reinterpret_cast<half4*>(lds + axX(0, row, 4 * lane)) = ha;
            *reinterpret_cast<half4*>(lds + axX(1, row, 4 * lane)) = hb;
        }
    }
    __syncthreads();

    // ==== P2: A-full. slotA[s] = X_{1-s} @ Gsel^T; wave owns 32 d-cols ====
    {
        const _Float16* Gsel = s ? Gf2 : Gf1;
        const int xo = 1 - s;
        f32x4 acc[4][2];
        #pragma unroll
        for (int i = 0; i < 4; ++i) { acc[i][0] = z; acc[i][1] = z; }
        #pragma unroll
        for (int ks = 0; ks < 8; ++ks) {
            half8 af[4];
            #pragma unroll
            for (int i = 0; i < 4; ++i)
                af[i] = *reinterpret_cast<const half8*>(lds + axX(xo, 16 * i + c, 32 * ks + 8 * kg));
            #pragma unroll
            for (int ct = 0; ct < 2; ++ct) {
                half8 bf = ld8(Gsel + (((2 * ws + ct) * 8 + ks) * 64 + lane) * 8);
                #pragma unroll
                for (int i = 0; i < 4; ++i)
                    acc[i][ct] = __builtin_amdgcn_mfma_f32_16x16x32_f16(af[i], bf, acc[i][ct], 0, 0, 0);
            }
        }
        #pragma unroll
        for (int i = 0; i < 4; ++i)
            #pragma unroll
            for (int ct = 0; ct < 2; ++ct)
                #pragma unroll
                for (int r = 0; r < 4; ++r)
                    *reinterpret_cast<_Float16*>(lds + axA(s, 16 * i + 4 * kg + r, 32 * ws + 16 * ct + c)) = (_Float16)acc[i][ct][r];
    }
    __syncthreads();

    // ==== P3: S (K=256) + softmax -> P[s]; 8 active waves (4 per side) ====
    if ((w & 4) == 0) {
        const int wa = w & 3;
        f32x4 Sacc[4] = {z, z, z, z};
        #pragma unroll
        for (int ks = 0; ks < 8; ++ks) {
            half8 af = *reinterpret_cast<const half8*>(lds + axX(s, 16 * wa + c, 32 * ks + 8 * kg));
            #pragma unroll
            for (int j = 0; j < 4; ++j) {
                half8 bfr = *reinterpret_cast<const half8*>(lds + axA(s, 16 * j + c, 32 * ks + 8 * kg));
                Sacc[j] = __builtin_amdgcn_mfma_f32_16x16x32_f16(af, bfr, Sacc[j], 0, 0, 0);
            }
        }
        #pragma unroll
        for (int r = 0; r < 4; ++r) {
            float m0 = fmaxf(fmaxf(Sacc[0][r], Sacc[1][r]), fmaxf(Sacc[2][r], Sacc[3][r]));
            m0 = fmaxf(m0, __shfl_xor(m0, 1));
            m0 = fmaxf(m0, __shfl_xor(m0, 2));
            m0 = fmaxf(m0, __shfl_xor(m0, 4));
            m0 = fmaxf(m0, __shfl_xor(m0, 8));
            float e0 = __expf(Sacc[0][r] - m0);
            float e1 = __expf(Sacc[1][r] - m0);
            float e2 = __expf(Sacc[2][r] - m0);
            float e3 = __expf(Sacc[3][r] - m0);
            float s0 = e0 + e1 + e2 + e3;
            s0 += __shfl_xor(s0, 1);
            s0 += __shfl_xor(s0, 2);
            s0 += __shfl_xor(s0, 4);
            s0 += __shfl_xor(s0, 8);
            const float inv = 1.f / s0;
            const int row = 16 * wa + 4 * kg + r;
            *reinterpret_cast<_Float16*>(lds + axP(s, row, 16 * 0 + c)) = (_Float16)(e0 * inv);
            *reinterpret_cast<_Float16*>(lds + axP(s, row, 16 * 1 + c)) = (_Float16)(e1 * inv);
            *reinterpret_cast<_Float16*>(lds + axP(s, row, 16 * 2 + c)) = (_Float16)(e2 * inv);
            *reinterpret_cast<_Float16*>(lds + axP(s, row, 16 * 3 + c)) = (_Float16)(e3 * inv);
        }
    }
    __syncthreads();

    // ==== P4: XT build over slotA (A dead); wave transposes 32 d-cols of X_s ====
    {
        #pragma unroll
        for (int jj = 0; jj < 4; ++jj) {
            half8 v = *reinterpret_cast<const half8*>(lds + axX(s, lane, 32 * ws + 8 * jj));
            #pragma unroll
            for (int e = 0; e < 8; ++e)
                *reinterpret_cast<_Float16*>(lds + axXT(s, 32 * ws + 8 * jj + e, lane)) = v[e];
        }
    }
    __syncthreads();

    // ==== P5: PV. g_s[:, 32ws..] = P_s @ X_s via XT; g overwrites X_s ====
    {
        half8 paf[4][2];
        #pragma unroll
        for (int i = 0; i < 4; ++i)
            #pragma unroll
            for (int ksp = 0; ksp < 2; ++ksp)
                paf[i][ksp] = *reinterpret_cast<const half8*>(lds + axP(s, 16 * i + c, 32 * ksp + 8 * kg));
        #pragma unroll
        for (int dt = 0; dt < 2; ++dt) {
            half8 bfr0 = *reinterpret_cast<const half8*>(lds + axXT(s, 32 * ws + 16 * dt + c, 8 * kg));
            half8 bfr1 = *reinterpret_cast<const half8*>(lds + axXT(s, 32 * ws + 16 * dt + c, 32 + 8 * kg));
            #pragma unroll
            for (int i = 0; i < 4; ++i) {
                f32x4 acc = z;
                acc = __builtin_amdgcn_mfma_f32_16x16x32_f16(paf[i][0], bfr0, acc, 0, 0, 0);
                acc = __builtin_amdgcn_mfma_f32_16x16x32_f16(paf[i][1], bfr1, acc, 0, 0, 0);
                #pragma unroll
                for (int r = 0; r < 4; ++r)
                    *reinterpret_cast<_Float16*>(lds + axX(s, 16 * i + 4 * kg + r, 32 * ws + 16 * dt + c)) = (_Float16)acc[r];
            }
        }
    }
    __syncthreads();

    // ==== P6: h-full = relu(g @ U + b1) -> h[64][512]; wave: 32 h-cols ====
    {
        f32x4 acc[4][2];
        #pragma unroll
        for (int i = 0; i < 4; ++i) { acc[i][0] = z; acc[i][1] = z; }
        #pragma unroll
        for (int ks = 0; ks < 16; ++ks) {
            const int side = ks >> 3, kk = ks & 7;
            half8 af[4];
            #pragma unroll
            for (int i = 0; i < 4; ++i)
                af[i] = *reinterpret_cast<const half8*>(lds + axX(side, 16 * i + c, 32 * kk + 8 * kg));
            #pragma unroll
            for (int ct = 0; ct < 2; ++ct) {
                half8 bf = ld8(UTf + (((2 * w + ct) * 16 + ks) * 64 + lane) * 8);
                #pragma unroll
                for (int i = 0; i < 4; ++i)
                    acc[i][ct] = __builtin_amdgcn_mfma_f32_16x16x32_f16(af[i], bf, acc[i][ct], 0, 0, 0);
            }
        }
        #pragma unroll
        for (int ct = 0; ct < 2; ++ct) {
            const float bb = b1[32 * w + 16 * ct + c];
            #pragma unroll
            for (int i = 0; i < 4; ++i)
                #pragma unroll
                for (int r = 0; r < 4; ++r)
                    *reinterpret_cast<_Float16*>(lds + axH(16 * i + 4 * kg + r, 32 * w + 16 * ct + c)) =
                        (_Float16)fmaxf(acc[i][ct][r] + bb, 0.f);
        }
    }
    __syncthreads();

    // ==== P7: out^T = W2T-rows x h (K=512) + b2; wave: 32 ocols ====
    {
        f32x4 oacc[2][4];
        #pragma unroll
        for (int i = 0; i < 2; ++i)
            #pragma unroll
            for (int nj = 0; nj < 4; ++nj) oacc[i][nj] = z;
        #pragma unroll
        for (int ks = 0; ks < 16; ++ks) {
            half8 bfr2[4];
            #pragma unroll
            for (int nj = 0; nj < 4; ++nj)
                bfr2[nj] = *reinterpret_cast<const half8*>(lds + axH(16 * nj + c, 32 * ks + 8 * kg));
            #pragma unroll
            for (int i = 0; i < 2; ++i) {
                half8 af2 = ld8(W2Tf + (((2 * w + i) * 16 + ks) * 64 + lane) * 8);
                #pragma unroll
                for (int nj = 0; nj < 4; ++nj)
                    oacc[i][nj] = __builtin_amdgcn_mfma_f32_16x16x32_f16(af2, bfr2[nj], oacc[i][nj], 0, 0, 0);
            }
        }
        // Epilogue: nj OUTER, i INNER (coalesced 128B spans per row)
        float* og = out + g * (size_t)(NB * HH);
        #pragma unroll
        for (int nj = 0; nj < 4; ++nj) {
            float* orow = og + (size_t)(16 * nj + c) * HH;
            #pragma unroll
            for (int i = 0; i < 2; ++i) {
                const int ocol0 = 32 * w + 16 * i + 4 * kg;
                const float4 b2v = *reinterpret_cast<const float4*>(b2 + ocol0);
                float4 res;
                res.x = oacc[i][nj][0] + b2v.x;
                res.y = oacc[i][nj][1] + b2v.y;
                res.z = oacc[i][nj][2] + b2v.z;
                res.w = oacc[i][nj][3] + b2v.w;
                *reinterpret_cast<float4*>(orow + ocol0) = res;
            }
        }
    }
}

// ---------------- launch ----------------

extern "C" void kernel_launch(void* const* d_in, const int* in_sizes, int n_in,
                              void* d_out, int out_size, void* d_ws, size_t ws_size,
                              hipStream_t stream) {
    (void)in_sizes; (void)n_in; (void)out_size; (void)ws_size;
    const float* x1  = (const float*)d_in[0];
    const float* x2  = (const float*)d_in[1];
    const float* Wq1 = (const float*)d_in[2];
    const float* Wk1 = (const float*)d_in[3];
    const float* Wv1 = (const float*)d_in[4];
    const float* Wq2 = (const float*)d_in[5];
    const float* Wk2 = (const float*)d_in[6];
    const float* Wv2 = (const float*)d_in[7];
    const float* W1  = (const float*)d_in[8];
    const float* b1  = (const float*)d_in[9];
    const float* W2  = (const float*)d_in[10];
    const float* b2  = (const float*)d_in[11];
    float* out = (float*)d_out;

    char* ws = (char*)d_ws;
    _Float16* Gf1  = (_Float16*)(ws + 0);        // 131072 (packed [16][8][64][8])
    _Float16* Gf2  = (_Float16*)(ws + 131072);   // 131072
    _Float16* UTf  = (_Float16*)(ws + 262144);   // 524288 (packed [32][16][64][8])
    _Float16* W2Tf = (_Float16*)(ws + 786432);   // 524288

    const float scale = 0.0625f;  // D^-0.5

    prep_all<<<384, 256, 0, stream>>>(Wq1, Wk1, Wv1, Wq2, Wk2, Wv2, W1, W2,
                                      Gf1, Gf2, UTf, W2Tf, scale);
    fused_kernel<<<NGROUP, 1024, 0, stream>>>(x1, x2, Gf1, Gf2, UTf, W2Tf, b1, b2, out);
}

// Round 18
// 360.237 us; speedup vs baseline: 4.7723x; 1.1483x over previous
//
#include <hip/hip_runtime.h>
#include <stdint.h>

#define NB 64
#define DD 256
#define HH 512
#define NGROUP 2048

typedef __attribute__((ext_vector_type(8))) _Float16 half8;
typedef __attribute__((ext_vector_type(4))) _Float16 half4;
typedef __attribute__((ext_vector_type(4))) float f32x4;

__device__ __forceinline__ half8 ld8(const _Float16* p) {
    return *reinterpret_cast<const half8*>(p);
}

// Fragment-packing index (R12, validated): matrix element [R][K]
__device__ __forceinline__ int fragidx(int R, int K, int NKS) {
    return (((R >> 4) * NKS + (K >> 5)) * 64 + (((K >> 3) & 3) * 16 + (R & 15))) * 8 + (K & 7);
}

// ---------------- prep v2 (R17, validated): LDS-staged, coalesced ----------------
__global__ void prep_all(const float* __restrict__ Wq1, const float* __restrict__ Wk1,
                         const float* __restrict__ Wv1, const float* __restrict__ Wq2,
                         const float* __restrict__ Wk2, const float* __restrict__ Wv2,
                         const float* __restrict__ W1, const float* __restrict__ W2,
                         _Float16* __restrict__ Gf1, _Float16* __restrict__ Gf2,
                         _Float16* __restrict__ UTf, _Float16* __restrict__ W2Tf,
                         float scale) {
    __shared__ __align__(16) float stage[8][512];
    __shared__ float tile[32][33];
    const int b = blockIdx.x, t = threadIdx.x;

    if (b < 64) {
        const int side = b >> 5;
        const int d0 = (b & 31) * 8;
        const float* Wq = side ? Wq2 : Wq1;
        const float* Wk = side ? Wk1 : Wk2;
        _Float16* G = side ? Gf2 : Gf1;
        #pragma unroll
        for (int it = 0; it < 4; ++it) {
            const int gi = t + 256 * it;
            const int row = gi >> 7, c4 = gi & 127;
            reinterpret_cast<float4*>(&stage[row][0])[c4] =
                reinterpret_cast<const float4*>(Wq + (size_t)(d0 + row) * HH)[c4];
        }
        __syncthreads();
        const int e = t;
        const float4* ka = reinterpret_cast<const float4*>(Wk + (size_t)e * HH);
        float s[8] = {0.f, 0.f, 0.f, 0.f, 0.f, 0.f, 0.f, 0.f};
        for (int j4 = 0; j4 < 128; ++j4) {
            const float4 v = ka[j4];
            #pragma unroll
            for (int dd = 0; dd < 8; ++dd) {
                const float4 q = reinterpret_cast<const float4*>(&stage[dd][0])[j4];
                s[dd] += v.x * q.x + v.y * q.y + v.z * q.z + v.w * q.w;
            }
        }
        #pragma unroll
        for (int dd = 0; dd < 8; ++dd)
            G[fragidx(d0 + dd, e, 8)] = (_Float16)(s[dd] * scale);
    } else if (b < 128) {
        const int bi = b - 64;
        const int half = bi >> 5;
        const int d0 = (bi & 31) * 8;
        const float* Wv = half ? Wv2 : Wv1;
        const float* W1p = W1 + (size_t)half * HH * HH;
        #pragma unroll
        for (int it = 0; it < 4; ++it) {
            const int gi = t + 256 * it;
            const int row = gi >> 7, c4 = gi & 127;
            reinterpret_cast<float4*>(&stage[row][0])[c4] =
                reinterpret_cast<const float4*>(Wv + (size_t)(d0 + row) * HH)[c4];
        }
        __syncthreads();
        const int o0 = t, o1 = t + 256;
        float s0[8] = {0.f, 0.f, 0.f, 0.f, 0.f, 0.f, 0.f, 0.f};
        float s1[8] = {0.f, 0.f, 0.f, 0.f, 0.f, 0.f, 0.f, 0.f};
        for (int j4 = 0; j4 < 128; ++j4) {
            float4 qv[8];
            #pragma unroll
            for (int dd = 0; dd < 8; ++dd)
                qv[dd] = reinterpret_cast<const float4*>(&stage[dd][0])[j4];
            #pragma unroll
            for (int k = 0; k < 4; ++k) {
                const int j = 4 * j4 + k;
                const float w0 = W1p[(size_t)j * HH + o0];
                const float w1 = W1p[(size_t)j * HH + o1];
                #pragma unroll
                for (int dd = 0; dd < 8; ++dd) {
                    const float q = (k == 0) ? qv[dd].x : (k == 1) ? qv[dd].y
                                  : (k == 2) ? qv[dd].z : qv[dd].w;
                    s0[dd] += q * w0;
                    s1[dd] += q * w1;
                }
            }
        }
        #pragma unroll
        for (int dd = 0; dd < 8; ++dd) {
            UTf[fragidx(o0, half * 256 + d0 + dd, 16)] = (_Float16)s0[dd];
            UTf[fragidx(o1, half * 256 + d0 + dd, 16)] = (_Float16)s1[dd];
        }
    } else {
        const int bi = b - 128;
        const int bk = (bi & 15) * 32;
        const int bh = (bi >> 4) * 32;
        const int tx = t & 31, ty = t >> 5;
        #pragma unroll
        for (int i = 0; i < 32; i += 8)
            tile[ty + i][tx] = W2[(size_t)(bh + ty + i) * HH + bk + tx];
        __syncthreads();
        #pragma unroll
        for (int i = 0; i < 32; i += 8) {
            const int R = bk + ty + i;
            const int K = bh + tx;
            W2Tf[fragidx(R, K, 16)] = (_Float16)tile[tx][ty + i];
        }
    }
}

// ---------------- main fused kernel (R17 + 2-deep SW pipeline in P2/P6/P7) ------
// 1024 thr (16 waves), 144 KiB LDS, 1 blk/CU, 4 waves/SIMD.
//   X  @ 0       [2][64][256] f16 ext-swz -> becomes g1,g2
//   A  @ 65536   [2][64][256] f16         -> XT [2][256][64] -> h [64][512]
//   P  @ 131072  [2][64][64] f16
#define ABASE 65536
#define PBASE 131072

__device__ __forceinline__ int axX(int side, int row, int ec) {
    return side * 32768 + row * 512 +
           ((2 * ec) ^ ((row & 7) << 4) ^ (((row >> 3) & 1) << 7));
}
__device__ __forceinline__ int axA(int side, int row, int ec) {
    return ABASE + side * 32768 + row * 512 +
           ((2 * ec) ^ ((row & 7) << 4) ^ (((row >> 3) & 1) << 7));
}
__device__ __forceinline__ int axXT(int side, int row, int ec) {   // [256][64], 128B rows
    return ABASE + side * 32768 + row * 128 + ((2 * ec) ^ ((row & 7) << 4));
}
__device__ __forceinline__ int axH(int row, int ec) {              // [64][512], 1024B rows
    return ABASE + row * 1024 +
           ((2 * ec) ^ ((row & 7) << 4) ^ (((row >> 3) & 1) << 7));
}
__device__ __forceinline__ int axP(int side, int row, int ec) {    // [64][64], 128B rows
    return PBASE + side * 8192 + row * 128 + ((2 * ec) ^ ((row & 7) << 4));
}

__global__ __launch_bounds__(1024, 4)
void fused_kernel(const float* __restrict__ x1g, const float* __restrict__ x2g,
                  const _Float16* __restrict__ Gf1, const _Float16* __restrict__ Gf2,
                  const _Float16* __restrict__ UTf, const _Float16* __restrict__ W2Tf,
                  const float* __restrict__ b1, const float* __restrict__ b2,
                  float* __restrict__ out) {
    __shared__ __align__(16) char lds[147456];

    const int tid = threadIdx.x;
    const int lane = tid & 63;
    const int w = tid >> 6;        // wave 0..15
    const int c = lane & 15;
    const int kg = lane >> 4;
    const int s = w >> 3;          // side (waves 0-7: side0, 8-15: side1)
    const int ws = w & 7;          // 32-wide strip index within side
    const size_t g = blockIdx.x;
    const f32x4 z = {0.f, 0.f, 0.f, 0.f};

    // ==== P1: stage x -> f16 LDS ====
    {
        const float* xs0 = x1g + g * (NB * DD);
        const float* xs1 = x2g + g * (NB * DD);
        #pragma unroll
        for (int it = 0; it < 4; ++it) {
            const int row = 4 * w + it;
            float4 a = reinterpret_cast<const float4*>(xs0 + row * DD)[lane];
            float4 b = reinterpret_cast<const float4*>(xs1 + row * DD)[lane];
            half4 ha, hb;
            ha[0] = (_Float16)a.x; ha[1] = (_Float16)a.y; ha[2] = (_Float16)a.z; ha[3] = (_Float16)a.w;
            hb[0] = (_Float16)b.x; hb[1] = (_Float16)b.y; hb[2] = (_Float16)b.z; hb[3] = (_Float16)b.w;
            *reinterpret_cast<half4*>(lds + axX(0, row, 4 * lane)) = ha;
            *reinterpret_cast<half4*>(lds + axX(1, row, 4 * lane)) = hb;
        }
    }
    __syncthreads();

    // ==== P2: A-full (2-deep pipelined). slotA[s] = X_{1-s} @ Gsel^T ====
    {
        const _Float16* Gsel = s ? Gf2 : Gf1;
        const int xo = 1 - s;
        f32x4 acc[4][2];
        #pragma unroll
        for (int i = 0; i < 4; ++i) { acc[i][0] = z; acc[i][1] = z; }
        half8 afb[2][4], bfb[2][2];
        #pragma unroll
        for (int i = 0; i < 4; ++i)
            afb[0][i] = *reinterpret_cast<const half8*>(lds + axX(xo, 16 * i + c, 8 * kg));
        #pragma unroll
        for (int ct = 0; ct < 2; ++ct)
            bfb[0][ct] = ld8(Gsel + (((2 * ws + ct) * 8) * 64 + lane) * 8);
        #pragma unroll
        for (int ks = 0; ks < 8; ++ks) {
            const int cur = ks & 1, nxt = cur ^ 1;
            if (ks < 7) {
                #pragma unroll
                for (int i = 0; i < 4; ++i)
                    afb[nxt][i] = *reinterpret_cast<const half8*>(lds + axX(xo, 16 * i + c, 32 * (ks + 1) + 8 * kg));
                #pragma unroll
                for (int ct = 0; ct < 2; ++ct)
                    bfb[nxt][ct] = ld8(Gsel + (((2 * ws + ct) * 8 + ks + 1) * 64 + lane) * 8);
            }
            __builtin_amdgcn_s_setprio(1);
            #pragma unroll
            for (int ct = 0; ct < 2; ++ct)
                #pragma unroll
                for (int i = 0; i < 4; ++i)
                    acc[i][ct] = __builtin_amdgcn_mfma_f32_16x16x32_f16(afb[cur][i], bfb[cur][ct], acc[i][ct], 0, 0, 0);
            __builtin_amdgcn_s_setprio(0);
        }
        #pragma unroll
        for (int i = 0; i < 4; ++i)
            #pragma unroll
            for (int ct = 0; ct < 2; ++ct)
                #pragma unroll
                for (int r = 0; r < 4; ++r)
                    *reinterpret_cast<_Float16*>(lds + axA(s, 16 * i + 4 * kg + r, 32 * ws + 16 * ct + c)) = (_Float16)acc[i][ct][r];
    }
    __syncthreads();

    // ==== P3: S (K=256) + softmax -> P[s]; 8 active waves (4 per side) ====
    if ((w & 4) == 0) {
        const int wa = w & 3;
        f32x4 Sacc[4] = {z, z, z, z};
        #pragma unroll
        for (int ks = 0; ks < 8; ++ks) {
            half8 af = *reinterpret_cast<const half8*>(lds + axX(s, 16 * wa + c, 32 * ks + 8 * kg));
            #pragma unroll
            for (int j = 0; j < 4; ++j) {
                half8 bfr = *reinterpret_cast<const half8*>(lds + axA(s, 16 * j + c, 32 * ks + 8 * kg));
                Sacc[j] = __builtin_amdgcn_mfma_f32_16x16x32_f16(af, bfr, Sacc[j], 0, 0, 0);
            }
        }
        #pragma unroll
        for (int r = 0; r < 4; ++r) {
            float m0 = fmaxf(fmaxf(Sacc[0][r], Sacc[1][r]), fmaxf(Sacc[2][r], Sacc[3][r]));
            m0 = fmaxf(m0, __shfl_xor(m0, 1));
            m0 = fmaxf(m0, __shfl_xor(m0, 2));
            m0 = fmaxf(m0, __shfl_xor(m0, 4));
            m0 = fmaxf(m0, __shfl_xor(m0, 8));
            float e0 = __expf(Sacc[0][r] - m0);
            float e1 = __expf(Sacc[1][r] - m0);
            float e2 = __expf(Sacc[2][r] - m0);
            float e3 = __expf(Sacc[3][r] - m0);
            float s0 = e0 + e1 + e2 + e3;
            s0 += __shfl_xor(s0, 1);
            s0 += __shfl_xor(s0, 2);
            s0 += __shfl_xor(s0, 4);
            s0 += __shfl_xor(s0, 8);
            const float inv = 1.f / s0;
            const int row = 16 * wa + 4 * kg + r;
            *reinterpret_cast<_Float16*>(lds + axP(s, row, 16 * 0 + c)) = (_Float16)(e0 * inv);
            *reinterpret_cast<_Float16*>(lds + axP(s, row, 16 * 1 + c)) = (_Float16)(e1 * inv);
            *reinterpret_cast<_Float16*>(lds + axP(s, row, 16 * 2 + c)) = (_Float16)(e2 * inv);
            *reinterpret_cast<_Float16*>(lds + axP(s, row, 16 * 3 + c)) = (_Float16)(e3 * inv);
        }
    }
    __syncthreads();

    // ==== P4: XT build over slotA (A dead); wave transposes 32 d-cols of X_s ====
    {
        #pragma unroll
        for (int jj = 0; jj < 4; ++jj) {
            half8 v = *reinterpret_cast<const half8*>(lds + axX(s, lane, 32 * ws + 8 * jj));
            #pragma unroll
            for (int e = 0; e < 8; ++e)
                *reinterpret_cast<_Float16*>(lds + axXT(s, 32 * ws + 8 * jj + e, lane)) = v[e];
        }
    }
    __syncthreads();

    // ==== P5: PV. g_s[:, 32ws..] = P_s @ X_s via XT; g overwrites X_s ====
    {
        half8 paf[4][2];
        #pragma unroll
        for (int i = 0; i < 4; ++i)
            #pragma unroll
            for (int ksp = 0; ksp < 2; ++ksp)
                paf[i][ksp] = *reinterpret_cast<const half8*>(lds + axP(s, 16 * i + c, 32 * ksp + 8 * kg));
        #pragma unroll
        for (int dt = 0; dt < 2; ++dt) {
            half8 bfr0 = *reinterpret_cast<const half8*>(lds + axXT(s, 32 * ws + 16 * dt + c, 8 * kg));
            half8 bfr1 = *reinterpret_cast<const half8*>(lds + axXT(s, 32 * ws + 16 * dt + c, 32 + 8 * kg));
            #pragma unroll
            for (int i = 0; i < 4; ++i) {
                f32x4 acc = z;
                acc = __builtin_amdgcn_mfma_f32_16x16x32_f16(paf[i][0], bfr0, acc, 0, 0, 0);
                acc = __builtin_amdgcn_mfma_f32_16x16x32_f16(paf[i][1], bfr1, acc, 0, 0, 0);
                #pragma unroll
                for (int r = 0; r < 4; ++r)
                    *reinterpret_cast<_Float16*>(lds + axX(s, 16 * i + 4 * kg + r, 32 * ws + 16 * dt + c)) = (_Float16)acc[r];
            }
        }
    }
    __syncthreads();

    // ==== P6: h-full (2-deep pipelined) = relu(g @ U + b1) -> h[64][512] ====
    {
        f32x4 acc[4][2];
        #pragma unroll
        for (int i = 0; i < 4; ++i) { acc[i][0] = z; acc[i][1] = z; }
        half8 afb[2][4], bfb[2][2];
        #pragma unroll
        for (int i = 0; i < 4; ++i)
            afb[0][i] = *reinterpret_cast<const half8*>(lds + axX(0, 16 * i + c, 8 * kg));
        #pragma unroll
        for (int ct = 0; ct < 2; ++ct)
            bfb[0][ct] = ld8(UTf + (((2 * w + ct) * 16) * 64 + lane) * 8);
        #pragma unroll
        for (int ks = 0; ks < 16; ++ks) {
            const int cur = ks & 1, nxt = cur ^ 1;
            if (ks < 15) {
                const int ks1 = ks + 1;
                const int side1 = ks1 >> 3, kk1 = ks1 & 7;
                #pragma unroll
                for (int i = 0; i < 4; ++i)
                    afb[nxt][i] = *reinterpret_cast<const half8*>(lds + axX(side1, 16 * i + c, 32 * kk1 + 8 * kg));
                #pragma unroll
                for (int ct = 0; ct < 2; ++ct)
                    bfb[nxt][ct] = ld8(UTf + (((2 * w + ct) * 16 + ks1) * 64 + lane) * 8);
            }
            __builtin_amdgcn_s_setprio(1);
            #pragma unroll
            for (int ct = 0; ct < 2; ++ct)
                #pragma unroll
                for (int i = 0; i < 4; ++i)
                    acc[i][ct] = __builtin_amdgcn_mfma_f32_16x16x32_f16(afb[cur][i], bfb[cur][ct], acc[i][ct], 0, 0, 0);
            __builtin_amdgcn_s_setprio(0);
        }
        #pragma unroll
        for (int ct = 0; ct < 2; ++ct) {
            const float bb = b1[32 * w + 16 * ct + c];
            #pragma unroll
            for (int i = 0; i < 4; ++i)
                #pragma unroll
                for (int r = 0; r < 4; ++r)
                    *reinterpret_cast<_Float16*>(lds + axH(16 * i + 4 * kg + r, 32 * w + 16 * ct + c)) =
                        (_Float16)fmaxf(acc[i][ct][r] + bb, 0.f);
        }
    }
    __syncthreads();

    // ==== P7: out^T (2-deep pipelined) = W2T-rows x h (K=512) + b2 ====
    {
        f32x4 oacc[2][4];
        #pragma unroll
        for (int i = 0; i < 2; ++i)
            #pragma unroll
            for (int nj = 0; nj < 4; ++nj) oacc[i][nj] = z;
        half8 bfrb[2][4], afb2[2][2];
        #pragma unroll
        for (int nj = 0; nj < 4; ++nj)
            bfrb[0][nj] = *reinterpret_cast<const half8*>(lds + axH(16 * nj + c, 8 * kg));
        #pragma unroll
        for (int i = 0; i < 2; ++i)
            afb2[0][i] = ld8(W2Tf + (((2 * w + i) * 16) * 64 + lane) * 8);
        #pragma unroll
        for (int ks = 0; ks < 16; ++ks) {
            const int cur = ks & 1, nxt = cur ^ 1;
            if (ks < 15) {
                #pragma unroll
                for (int nj = 0; nj < 4; ++nj)
                    bfrb[nxt][nj] = *reinterpret_cast<const half8*>(lds + axH(16 * nj + c, 32 * (ks + 1) + 8 * kg));
                #pragma unroll
                for (int i = 0; i < 2; ++i)
                    afb2[nxt][i] = ld8(W2Tf + (((2 * w + i) * 16 + ks + 1) * 64 + lane) * 8);
            }
            __builtin_amdgcn_s_setprio(1);
            #pragma unroll
            for (int i = 0; i < 2; ++i)
                #pragma unroll
                for (int nj = 0; nj < 4; ++nj)
                    oacc[i][nj] = __builtin_amdgcn_mfma_f32_16x16x32_f16(afb2[cur][i], bfrb[cur][nj], oacc[i][nj], 0, 0, 0);
            __builtin_amdgcn_s_setprio(0);
        }
        // Epilogue: nj OUTER, i INNER (coalesced 128B spans per row)
        float* og = out + g * (size_t)(NB * HH);
        #pragma unroll
        for (int nj = 0; nj < 4; ++nj) {
            float* orow = og + (size_t)(16 * nj + c) * HH;
            #pragma unroll
            for (int i = 0; i < 2; ++i) {
                const int ocol0 = 32 * w + 16 * i + 4 * kg;
                const float4 b2v = *reinterpret_cast<const float4*>(b2 + ocol0);
                float4 res;
                res.x = oacc[i][nj][0] + b2v.x;
                res.y = oacc[i][nj][1] + b2v.y;
                res.z = oacc[i][nj][2] + b2v.z;
                res.w = oacc[i][nj][3] + b2v.w;
                *reinterpret_cast<float4*>(orow + ocol0) = res;
            }
        }
    }
}

// ---------------- launch ----------------

extern "C" void kernel_launch(void* const* d_in, const int* in_sizes, int n_in,
                              void* d_out, int out_size, void* d_ws, size_t ws_size,
                              hipStream_t stream) {
    (void)in_sizes; (void)n_in; (void)out_size; (void)ws_size;
    const float* x1  = (const float*)d_in[0];
    const float* x2  = (const float*)d_in[1];
    const float* Wq1 = (const float*)d_in[2];
    const float* Wk1 = (const float*)d_in[3];
    const float* Wv1 = (const float*)d_in[4];
    const float* Wq2 = (const float*)d_in[5];
    const float* Wk2 = (const float*)d_in[6];
    const float* Wv2 = (const float*)d_in[7];
    const float* W1  = (const float*)d_in[8];
    const float* b1  = (const float*)d_in[9];
    const float* W2  = (const float*)d_in[10];
    const float* b2  = (const float*)d_in[11];
    float* out = (float*)d_out;

    char* ws = (char*)d_ws;
    _Float16* Gf1  = (_Float16*)(ws + 0);        // 131072 (packed [16][8][64][8])
    _Float16* Gf2  = (_Float16*)(ws + 131072);   // 131072
    _Float16* UTf  = (_Float16*)(ws + 262144);   // 524288 (packed [32][16][64][8])
    _Float16* W2Tf = (_Float16*)(ws + 786432);   // 524288

    const float scale = 0.0625f;  // D^-0.5

    prep_all<<<384, 256, 0, stream>>>(Wq1, Wk1, Wv1, Wq2, Wk2, Wv2, W1, W2,
                                      Gf1, Gf2, UTf, W2Tf, scale);
    fused_kernel<<<NGROUP, 1024, 0, stream>>>(x1, x2, Gf1, Gf2, UTf, W2Tf, b1, b2, out);
}